// Round 1
// baseline (682.026 us; speedup 1.0000x reference)
//
#include <hip/hip_runtime.h>
#include <stdint.h>

#define B_  4
#define S_  2048
#define D_  1024
#define H_  16
#define DK_ 64
#define M_  (B_ * S_)   // 8192

typedef __attribute__((ext_vector_type(4))) float  f32x4;
typedef __attribute__((ext_vector_type(8))) __bf16 bf16x8;
typedef __attribute__((ext_vector_type(4))) unsigned short us4;

__device__ __forceinline__ unsigned short cvt_bf16(float f) {
  unsigned u = __float_as_uint(f);
  return (unsigned short)((u + 0x7fffu + ((u >> 16) & 1u)) >> 16);
}

__device__ __forceinline__ f32x4 mfma16(bf16x8 a, bf16x8 b, f32x4 c) {
  return __builtin_amdgcn_mfma_f32_16x16x32_bf16(a, b, c, 0, 0, 0);
}

__device__ __forceinline__ void async16(const void* g, void* l) {
  __builtin_amdgcn_global_load_lds(
      (const __attribute__((address_space(1))) void*)g,
      (__attribute__((address_space(3))) void*)l, 16, 0, 0);
}

// ---------------------------------------------------------------- cast kernel
__global__ void cast_f32_bf16(const float* __restrict__ in,
                              unsigned short* __restrict__ out, int n4) {
  int i = blockIdx.x * blockDim.x + threadIdx.x;
  if (i >= n4) return;
  f32x4 v = ((const f32x4*)in)[i];
  us4 o;
  o[0] = cvt_bf16(v[0]); o[1] = cvt_bf16(v[1]);
  o[2] = cvt_bf16(v[2]); o[3] = cvt_bf16(v[3]);
  ((us4*)out)[i] = o;
}

// ---------------------------------------------------------------- GEMM C = A @ W^T
// A: [M,K] bf16 row-major.  Bm (=W): [N,K] bf16 row-major.
// OUTMODE 0: bf16 [M,N].  1: bf16 transposed V layout [(m>>11)*1024+n][m&2047].
// OUTMODE 2: f32 [M,N].
template <int OUTMODE>
__global__ __launch_bounds__(256) void gemm_bt(
    const unsigned short* __restrict__ A,
    const unsigned short* __restrict__ Bm,
    void* __restrict__ Cp, int Mdim, int Ndim, int Kdim) {
  constexpr int BM = 128, BN = 128, BK = 32;
  __shared__ __align__(16) unsigned short As[BM * BK];
  __shared__ __align__(16) unsigned short Bs[BN * BK];

  const int tid = threadIdx.x;
  const int w = tid >> 6, l = tid & 63;
  const int l16 = l & 15, lg = l >> 4;
  const int wr = w >> 1, wc = w & 1;
  const int rowA0 = blockIdx.y * BM;
  const int rowB0 = blockIdx.x * BN;
  const int l4 = l >> 2;          // row within a 16-row chunk
  const int lk = (l & 3) * 8;     // k-element offset

  f32x4 acc[4][4] = {};

  for (int kt = 0; kt < Kdim; kt += BK) {
#pragma unroll
    for (int j = 0; j < 2; ++j) {
      const int chunk = j * 4 + w;        // 0..7, wave-uniform
      const int r = chunk * 16 + l4;
      async16(A  + (size_t)(rowA0 + r) * Kdim + kt + lk, &As[chunk * 512]);
      async16(Bm + (size_t)(rowB0 + r) * Kdim + kt + lk, &Bs[chunk * 512]);
    }
    __syncthreads();
    bf16x8 af[4], bfr[4];
#pragma unroll
    for (int m = 0; m < 4; ++m)
      af[m] = *(const bf16x8*)&As[(wr * 64 + m * 16 + l16) * BK + lg * 8];
#pragma unroll
    for (int n = 0; n < 4; ++n)
      bfr[n] = *(const bf16x8*)&Bs[(wc * 64 + n * 16 + l16) * BK + lg * 8];
#pragma unroll
    for (int m = 0; m < 4; ++m)
#pragma unroll
      for (int n = 0; n < 4; ++n)
        acc[m][n] = mfma16(af[m], bfr[n], acc[m][n]);
    __syncthreads();
  }

  const int rb = rowA0 + wr * 64;
  const int cb = rowB0 + wc * 64;
  if constexpr (OUTMODE == 2) {
    float* C = (float*)Cp;
#pragma unroll
    for (int m = 0; m < 4; ++m)
#pragma unroll
      for (int n = 0; n < 4; ++n) {
        const int r0 = rb + m * 16 + lg * 4;
        const int c0 = cb + n * 16 + l16;
#pragma unroll
        for (int j = 0; j < 4; ++j)
          C[(size_t)(r0 + j) * Ndim + c0] = acc[m][n][j];
      }
  } else if constexpr (OUTMODE == 0) {
    unsigned short* C = (unsigned short*)Cp;
#pragma unroll
    for (int m = 0; m < 4; ++m)
#pragma unroll
      for (int n = 0; n < 4; ++n) {
        const int r0 = rb + m * 16 + lg * 4;
        const int c0 = cb + n * 16 + l16;
#pragma unroll
        for (int j = 0; j < 4; ++j)
          C[(size_t)(r0 + j) * Ndim + c0] = cvt_bf16(acc[m][n][j]);
      }
  } else {  // V transposed: Vt[(b*1024 + n)][s], s = m & 2047, b = m >> 11
    unsigned short* C = (unsigned short*)Cp;
#pragma unroll
    for (int m = 0; m < 4; ++m)
#pragma unroll
      for (int n = 0; n < 4; ++n) {
        const int r0 = rb + m * 16 + lg * 4;   // multiple of 4
        const int c0 = cb + n * 16 + l16;
        us4 v;
#pragma unroll
        for (int j = 0; j < 4; ++j) v[j] = cvt_bf16(acc[m][n][j]);
        *(us4*)&C[((size_t)(r0 >> 11) * 1024 + c0) * 2048 + (r0 & 2047)] = v;
      }
  }
}

// ---------------------------------------------------------------- flash attention
// Q,K: [B*S, D] bf16 (head-packed).  Vt: [(b*1024 + h*64 + dk)][s] bf16.
// O: [B*S, D] bf16.  One block = one (b,h) x 64-row q-tile; 4 waves x 16 rows.
__global__ __launch_bounds__(256) void flash_attn(
    const unsigned short* __restrict__ Q,
    const unsigned short* __restrict__ K,
    const unsigned short* __restrict__ Vt,
    unsigned short* __restrict__ O) {
  const int qt = blockIdx.x;          // 0..31
  const int bh = blockIdx.y;          // 0..63
  const int b = bh >> 4, h = bh & 15;
  const int tid = threadIdx.x;
  const int w = tid >> 6, l = tid & 63;
  const int l16 = l & 15, lg = l >> 4;

  __shared__ __align__(16) unsigned short Plds[4][16][72];  // per-wave P tile

  // Q fragments for this wave's 16 rows
  const int qrow = qt * 64 + w * 16 + l16;
  const size_t qb = ((size_t)(b * S_) + qrow) * D_ + h * DK_;
  bf16x8 qf[2];
  qf[0] = *(const bf16x8*)&Q[qb + lg * 8];
  qf[1] = *(const bf16x8*)&Q[qb + 32 + lg * 8];

  float m_run[4] = {-INFINITY, -INFINITY, -INFINITY, -INFINITY};
  float s_run[4] = {0.f, 0.f, 0.f, 0.f};
  f32x4 o_acc[4] = {};

  const size_t kbase = (size_t)b * S_ * D_ + h * DK_;
  const size_t vbase = ((size_t)b * D_ + h * DK_) * S_;
  const int rbase = qt * 64 + w * 16 + lg * 4;  // + j = global q row

  for (int kvt = 0; kvt <= qt; ++kvt) {
    const int kv0 = kvt * 64;
    f32x4 sc[4] = {};
#pragma unroll
    for (int nc = 0; nc < 4; ++nc) {
      const size_t kr = kbase + (size_t)(kv0 + nc * 16 + l16) * D_;
      sc[nc] = mfma16(qf[0], *(const bf16x8*)&K[kr + lg * 8], sc[nc]);
      sc[nc] = mfma16(qf[1], *(const bf16x8*)&K[kr + 32 + lg * 8], sc[nc]);
    }
#pragma unroll
    for (int nc = 0; nc < 4; ++nc)
#pragma unroll
      for (int j = 0; j < 4; ++j) sc[nc][j] *= 0.125f;
    if (kvt == qt) {  // diagonal tile: causal mask
#pragma unroll
      for (int nc = 0; nc < 4; ++nc) {
        const int col = kv0 + nc * 16 + l16;
#pragma unroll
        for (int j = 0; j < 4; ++j)
          if (col > rbase + j) sc[nc][j] = -INFINITY;
      }
    }
    // online softmax (rows = lg*4+j, 16 lanes per row-group hold cols)
    float mnew[4], rsum[4];
#pragma unroll
    for (int j = 0; j < 4; ++j) {
      float t = fmaxf(fmaxf(sc[0][j], sc[1][j]), fmaxf(sc[2][j], sc[3][j]));
      t = fmaxf(t, __shfl_xor(t, 1));
      t = fmaxf(t, __shfl_xor(t, 2));
      t = fmaxf(t, __shfl_xor(t, 4));
      t = fmaxf(t, __shfl_xor(t, 8));
      mnew[j] = fmaxf(m_run[j], t);
      rsum[j] = 0.f;
    }
#pragma unroll
    for (int nc = 0; nc < 4; ++nc)
#pragma unroll
      for (int j = 0; j < 4; ++j) {
        const float p = __expf(sc[nc][j] - mnew[j]);
        rsum[j] += p;
        Plds[w][lg * 4 + j][nc * 16 + l16] = cvt_bf16(p);
      }
#pragma unroll
    for (int j = 0; j < 4; ++j) {
      float t = rsum[j];
      t += __shfl_xor(t, 1);
      t += __shfl_xor(t, 2);
      t += __shfl_xor(t, 4);
      t += __shfl_xor(t, 8);
      const float alpha = __expf(m_run[j] - mnew[j]);
      s_run[j] = s_run[j] * alpha + t;
      m_run[j] = mnew[j];
#pragma unroll
      for (int d = 0; d < 4; ++d) o_acc[d][j] *= alpha;
    }
    __asm__ volatile("s_waitcnt lgkmcnt(0)" ::: "memory");  // P visible wave-wide
    bf16x8 pa0 = *(const bf16x8*)&Plds[w][l16][lg * 8];
    bf16x8 pa1 = *(const bf16x8*)&Plds[w][l16][32 + lg * 8];
#pragma unroll
    for (int d = 0; d < 4; ++d) {
      const size_t vr = vbase + (size_t)(d * 16 + l16) * S_ + kv0;
      o_acc[d] = mfma16(pa0, *(const bf16x8*)&Vt[vr + lg * 8], o_acc[d]);
      o_acc[d] = mfma16(pa1, *(const bf16x8*)&Vt[vr + 32 + lg * 8], o_acc[d]);
    }
  }

#pragma unroll
  for (int d = 0; d < 4; ++d)
#pragma unroll
    for (int j = 0; j < 4; ++j) {
      const float v = o_acc[d][j] / s_run[j];
      O[((size_t)(b * S_) + rbase + j) * D_ + h * DK_ + d * 16 + l16] =
          cvt_bf16(v);
    }
}

// ---------------------------------------------------------------- launch
extern "C" void kernel_launch(void* const* d_in, const int* in_sizes, int n_in,
                              void* d_out, int out_size, void* d_ws,
                              size_t ws_size, hipStream_t stream) {
  const float* x  = (const float*)d_in[0];
  const float* Wq = (const float*)d_in[1];
  const float* Wk = (const float*)d_in[2];
  const float* Wv = (const float*)d_in[3];
  const float* Wo = (const float*)d_in[4];

  const size_t XN = (size_t)M_ * D_;   // 8388608
  const size_t WN = (size_t)D_ * D_;   // 1048576
  unsigned short* xb  = (unsigned short*)d_ws;
  unsigned short* Wqb = xb + XN;
  unsigned short* Wkb = Wqb + WN;
  unsigned short* Wvb = Wkb + WN;
  unsigned short* Wob = Wvb + WN;
  unsigned short* Qb  = Wob + WN;
  unsigned short* Kb  = Qb + XN;
  unsigned short* Vtb = Kb + XN;
  unsigned short* Ob  = Vtb + XN;

  cast_f32_bf16<<<(int)(XN / 4 / 256), 256, 0, stream>>>(x, xb, (int)(XN / 4));
  cast_f32_bf16<<<(int)(WN / 4 / 256), 256, 0, stream>>>(Wq, Wqb, (int)(WN / 4));
  cast_f32_bf16<<<(int)(WN / 4 / 256), 256, 0, stream>>>(Wk, Wkb, (int)(WN / 4));
  cast_f32_bf16<<<(int)(WN / 4 / 256), 256, 0, stream>>>(Wv, Wvb, (int)(WN / 4));
  cast_f32_bf16<<<(int)(WN / 4 / 256), 256, 0, stream>>>(Wo, Wob, (int)(WN / 4));

  dim3 gg(D_ / 128, M_ / 128);  // (8, 64)
  gemm_bt<0><<<gg, 256, 0, stream>>>(xb, Wqb, Qb, M_, D_, D_);
  gemm_bt<0><<<gg, 256, 0, stream>>>(xb, Wkb, Kb, M_, D_, D_);
  gemm_bt<1><<<gg, 256, 0, stream>>>(xb, Wvb, Vtb, M_, D_, D_);

  flash_attn<<<dim3(S_ / 64, B_ * H_), 256, 0, stream>>>(Qb, Kb, Vtb, Ob);

  gemm_bt<2><<<gg, 256, 0, stream>>>(Ob, Wob, d_out, M_, D_, D_);
}

// Round 4
// 502.362 us; speedup vs baseline: 1.3576x; 1.3576x over previous
//
#include <hip/hip_runtime.h>
#include <stdint.h>

#define B_  4
#define S_  2048
#define D_  1024
#define H_  16
#define DK_ 64
#define M_  (B_ * S_)   // 8192

typedef __attribute__((ext_vector_type(4))) float  f32x4;
typedef __attribute__((ext_vector_type(8))) __bf16 bf16x8;
typedef __attribute__((ext_vector_type(4))) unsigned short us4;

__device__ __forceinline__ unsigned short cvt_bf16(float f) {
  unsigned u = __float_as_uint(f);
  return (unsigned short)((u + 0x7fffu + ((u >> 16) & 1u)) >> 16);
}

__device__ __forceinline__ f32x4 mfma16(bf16x8 a, bf16x8 b, f32x4 c) {
  return __builtin_amdgcn_mfma_f32_16x16x32_bf16(a, b, c, 0, 0, 0);
}

__device__ __forceinline__ void async16(const void* g, void* l) {
  __builtin_amdgcn_global_load_lds(
      (const __attribute__((address_space(1))) void*)g,
      (__attribute__((address_space(3))) void*)l, 16, 0, 0);
}

// ---------------------------------------------------------------- cast kernel
__global__ void cast_f32_bf16(const float* __restrict__ in,
                              unsigned short* __restrict__ out, int n4) {
  int i = blockIdx.x * blockDim.x + threadIdx.x;
  if (i >= n4) return;
  f32x4 v = ((const f32x4*)in)[i];
  us4 o;
  o[0] = cvt_bf16(v[0]); o[1] = cvt_bf16(v[1]);
  o[2] = cvt_bf16(v[2]); o[3] = cvt_bf16(v[3]);
  ((us4*)out)[i] = o;
}

// ---------------------------------------------------------------- GEMM C = A @ W^T
// A: [M,K] bf16 row-major.  Bm (=W): [N,K] bf16 row-major.
// OUTMODE 0: bf16 [M,N].  1: bf16 transposed V layout [(m>>11)*1024+n][m&2047].
// OUTMODE 2: f32 [M,N].
template <int OUTMODE>
__global__ __launch_bounds__(256) void gemm_bt(
    const unsigned short* __restrict__ A,
    const unsigned short* __restrict__ Bm,
    void* __restrict__ Cp, int Mdim, int Ndim, int Kdim) {
  constexpr int BM = 128, BN = 128, BK = 32;
  __shared__ __align__(16) unsigned short As[BM * BK];
  __shared__ __align__(16) unsigned short Bs[BN * BK];

  const int tid = threadIdx.x;
  const int w = tid >> 6, l = tid & 63;
  const int l16 = l & 15, lg = l >> 4;
  const int wr = w >> 1, wc = w & 1;
  const int rowA0 = blockIdx.y * BM;
  const int rowB0 = blockIdx.x * BN;
  const int l4 = l >> 2;          // row within a 16-row chunk
  const int lk = (l & 3) * 8;     // k-element offset

  f32x4 acc[4][4] = {};

  for (int kt = 0; kt < Kdim; kt += BK) {
#pragma unroll
    for (int j = 0; j < 2; ++j) {
      const int chunk = j * 4 + w;        // 0..7, wave-uniform
      const int r = chunk * 16 + l4;
      async16(A  + (size_t)(rowA0 + r) * Kdim + kt + lk, &As[chunk * 512]);
      async16(Bm + (size_t)(rowB0 + r) * Kdim + kt + lk, &Bs[chunk * 512]);
    }
    __syncthreads();
    bf16x8 af[4], bfr[4];
#pragma unroll
    for (int m = 0; m < 4; ++m)
      af[m] = *(const bf16x8*)&As[(wr * 64 + m * 16 + l16) * BK + lg * 8];
#pragma unroll
    for (int n = 0; n < 4; ++n)
      bfr[n] = *(const bf16x8*)&Bs[(wc * 64 + n * 16 + l16) * BK + lg * 8];
#pragma unroll
    for (int m = 0; m < 4; ++m)
#pragma unroll
      for (int n = 0; n < 4; ++n)
        acc[m][n] = mfma16(af[m], bfr[n], acc[m][n]);
    __syncthreads();
  }

  const int rb = rowA0 + wr * 64;
  const int cb = rowB0 + wc * 64;
  if constexpr (OUTMODE == 2) {
    float* C = (float*)Cp;
#pragma unroll
    for (int m = 0; m < 4; ++m)
#pragma unroll
      for (int n = 0; n < 4; ++n) {
        const int r0 = rb + m * 16 + lg * 4;
        const int c0 = cb + n * 16 + l16;
#pragma unroll
        for (int j = 0; j < 4; ++j)
          C[(size_t)(r0 + j) * Ndim + c0] = acc[m][n][j];
      }
  } else if constexpr (OUTMODE == 0) {
    unsigned short* C = (unsigned short*)Cp;
#pragma unroll
    for (int m = 0; m < 4; ++m)
#pragma unroll
      for (int n = 0; n < 4; ++n) {
        const int r0 = rb + m * 16 + lg * 4;
        const int c0 = cb + n * 16 + l16;
#pragma unroll
        for (int j = 0; j < 4; ++j)
          C[(size_t)(r0 + j) * Ndim + c0] = cvt_bf16(acc[m][n][j]);
      }
  } else {  // V transposed: Vt[(b*1024 + n)][s], s = m & 2047, b = m >> 11
    unsigned short* C = (unsigned short*)Cp;
#pragma unroll
    for (int m = 0; m < 4; ++m)
#pragma unroll
      for (int n = 0; n < 4; ++n) {
        const int r0 = rb + m * 16 + lg * 4;   // multiple of 4
        const int c0 = cb + n * 16 + l16;
        us4 v;
#pragma unroll
        for (int j = 0; j < 4; ++j) v[j] = cvt_bf16(acc[m][n][j]);
        *(us4*)&C[((size_t)(r0 >> 11) * 1024 + c0) * 2048 + (r0 & 2047)] = v;
      }
  }
}

// ---------------------------------------------------------------- flash attention
// Q,K: [B*S, D] bf16 (head-packed).  Vt: [(b*1024 + h*64 + dk)][s] bf16.
// O: [B*S, D] bf16.
// One block = one (b,h) x paired q-tiles {x, 31-x} (64 rows each).
// 4 waves x (16 rows of A + 16 rows of B). Uniform 33 KV-iterations per block.
// K/V tiles staged once per iteration in LDS (XOR-swizzled), shared by all
// waves and by both q-tile sets.
__global__ __launch_bounds__(256, 4) void flash_attn(
    const unsigned short* __restrict__ Q,
    const unsigned short* __restrict__ K,
    const unsigned short* __restrict__ Vt,
    unsigned short* __restrict__ O) {
  const int x  = blockIdx.x;          // 0..15 pair index
  const int bh = blockIdx.y;          // 0..63
  const int b = bh >> 4, h = bh & 15;
  const int tid = threadIdx.x;
  const int w = tid >> 6, l = tid & 63;
  const int l16 = l & 15, lg = l >> 4;

  __shared__ __align__(16) unsigned short Ks[64 * 64];       // [s][dk] swizzled
  __shared__ __align__(16) unsigned short Vs[64 * 64];       // [dk][s] swizzled
  __shared__ __align__(16) unsigned short PA[4][16][72];
  __shared__ __align__(16) unsigned short PB[4][16][72];

  const int tA = x, tB = 31 - x;      // tA < tB always

  const size_t qkbase = (size_t)(b * S_) * D_ + h * DK_;
  const size_t vbase  = ((size_t)(b * D_) + h * DK_) * S_;

  const int rA = tA * 64 + w * 16 + l16;
  const int rB = tB * 64 + w * 16 + l16;
  bf16x8 qfA[2], qfB[2];
  qfA[0] = *(const bf16x8*)&Q[qkbase + (size_t)rA * D_ + lg * 8];
  qfA[1] = *(const bf16x8*)&Q[qkbase + (size_t)rA * D_ + 32 + lg * 8];
  qfB[0] = *(const bf16x8*)&Q[qkbase + (size_t)rB * D_ + lg * 8];
  qfB[1] = *(const bf16x8*)&Q[qkbase + (size_t)rB * D_ + 32 + lg * 8];

  float mA[4], sA[4], mB[4], sB[4];
  f32x4 oA[4] = {}, oB[4] = {};
#pragma unroll
  for (int j = 0; j < 4; ++j) {
    mA[j] = mB[j] = -INFINITY;
    sA[j] = sB[j] = 0.f;
  }

  const int rbA = tA * 64 + w * 16 + lg * 4;  // +j = global q row (set A)
  const int rbB = tB * 64 + w * 16 + lg * 4;

  // online-softmax + P-store for one 16x64 score tile
  auto smx = [&](f32x4* sc, float* mr, float* sr, f32x4* oa,
                 unsigned short (*P)[72], bool diag, int rb, int kv0) {
#pragma unroll
    for (int nc = 0; nc < 4; ++nc)
#pragma unroll
      for (int j = 0; j < 4; ++j) sc[nc][j] *= 0.125f;
    if (diag) {
#pragma unroll
      for (int nc = 0; nc < 4; ++nc) {
        const int col = kv0 + nc * 16 + l16;
#pragma unroll
        for (int j = 0; j < 4; ++j)
          if (col > rb + j) sc[nc][j] = -INFINITY;
      }
    }
#pragma unroll
    for (int j = 0; j < 4; ++j) {
      float t = fmaxf(fmaxf(sc[0][j], sc[1][j]), fmaxf(sc[2][j], sc[3][j]));
      t = fmaxf(t, __shfl_xor(t, 1));
      t = fmaxf(t, __shfl_xor(t, 2));
      t = fmaxf(t, __shfl_xor(t, 4));
      t = fmaxf(t, __shfl_xor(t, 8));
      const float mnew = fmaxf(mr[j], t);
      float rsum = 0.f;
#pragma unroll
      for (int nc = 0; nc < 4; ++nc) {
        const float p = __expf(sc[nc][j] - mnew);
        rsum += p;
        P[lg * 4 + j][nc * 16 + l16] = cvt_bf16(p);
      }
      rsum += __shfl_xor(rsum, 1);
      rsum += __shfl_xor(rsum, 2);
      rsum += __shfl_xor(rsum, 4);
      rsum += __shfl_xor(rsum, 8);
      const float alpha = __expf(mr[j] - mnew);
      sr[j] = sr[j] * alpha + rsum;
      mr[j] = mnew;
#pragma unroll
      for (int d = 0; d < 4; ++d) oa[d][j] *= alpha;
    }
  };

  for (int kv = 0; kv <= tB; ++kv) {
    const int kv0 = kv * 64;
    if (kv) __syncthreads();  // previous tile fully consumed before overwrite
    // stage K tile [64 s][64 dk] and V tile [64 dk][64 s], 16B chunks,
    // inverse-swizzled source so swizzled reads see logical data (rule #21)
#pragma unroll
    for (int c = 0; c < 2; ++c) {
      const int ci = c * 256 + w * 64;  // wave-uniform chunk base
      const int i  = ci + l;            // per-lane chunk 0..511
      const int r  = i >> 3;            // tile row
      const int cc = (i & 7) ^ (r & 7); // swizzled 16B column
      async16(K  + qkbase + (size_t)(kv0 + r) * D_ + cc * 8, &Ks[ci * 8]);
      async16(Vt + vbase  + (size_t)r * S_ + kv0 + cc * 8,   &Vs[ci * 8]);
    }
    __syncthreads();  // compiler drains vmcnt before barrier -> staging done

    const bool doA = (kv <= tA);  // wave-uniform
    f32x4 scA[4] = {}, scB[4] = {};
#pragma unroll
    for (int nc = 0; nc < 4; ++nc) {
      const int r = nc * 16 + l16;
#pragma unroll
      for (int ks = 0; ks < 2; ++ks) {
        const int byte = (r * 128 + ks * 64 + lg * 16) ^ ((r & 7) << 4);
        bf16x8 kf = *(const bf16x8*)((const char*)Ks + byte);
        if (doA) scA[nc] = mfma16(qfA[ks], kf, scA[nc]);
        scB[nc] = mfma16(qfB[ks], kf, scB[nc]);
      }
    }

    if (doA) smx(scA, mA, sA, oA, PA[w], kv == tA, rbA, kv0);
    smx(scB, mB, sB, oB, PB[w], kv == tB, rbB, kv0);

    bf16x8 paA[2], paB[2];
    if (doA) {
      paA[0] = *(const bf16x8*)&PA[w][l16][lg * 8];
      paA[1] = *(const bf16x8*)&PA[w][l16][32 + lg * 8];
    }
    paB[0] = *(const bf16x8*)&PB[w][l16][lg * 8];
    paB[1] = *(const bf16x8*)&PB[w][l16][32 + lg * 8];

#pragma unroll
    for (int d = 0; d < 4; ++d) {
      const int r = d * 16 + l16;
#pragma unroll
      for (int ks = 0; ks < 2; ++ks) {
        const int byte = (r * 128 + ks * 64 + lg * 16) ^ ((r & 7) << 4);
        bf16x8 vf = *(const bf16x8*)((const char*)Vs + byte);
        if (doA) oA[d] = mfma16(paA[ks], vf, oA[d]);
        oB[d] = mfma16(paB[ks], vf, oB[d]);
      }
    }
  }

#pragma unroll
  for (int d = 0; d < 4; ++d)
#pragma unroll
    for (int j = 0; j < 4; ++j) {
      O[((size_t)(b * S_) + rbA + j) * D_ + h * DK_ + d * 16 + l16] =
          cvt_bf16(oA[d][j] / sA[j]);
      O[((size_t)(b * S_) + rbB + j) * D_ + h * DK_ + d * 16 + l16] =
          cvt_bf16(oB[d][j] / sB[j]);
    }
}

// ---------------------------------------------------------------- launch
extern "C" void kernel_launch(void* const* d_in, const int* in_sizes, int n_in,
                              void* d_out, int out_size, void* d_ws,
                              size_t ws_size, hipStream_t stream) {
  const float* x  = (const float*)d_in[0];
  const float* Wq = (const float*)d_in[1];
  const float* Wk = (const float*)d_in[2];
  const float* Wv = (const float*)d_in[3];
  const float* Wo = (const float*)d_in[4];

  const size_t XN = (size_t)M_ * D_;   // 8388608
  const size_t WN = (size_t)D_ * D_;   // 1048576
  unsigned short* xb  = (unsigned short*)d_ws;
  unsigned short* Wqb = xb + XN;
  unsigned short* Wkb = Wqb + WN;
  unsigned short* Wvb = Wkb + WN;
  unsigned short* Wob = Wvb + WN;
  unsigned short* Qb  = Wob + WN;
  unsigned short* Kb  = Qb + XN;
  unsigned short* Vtb = Kb + XN;
  unsigned short* Ob  = Vtb + XN;

  cast_f32_bf16<<<(int)(XN / 4 / 256), 256, 0, stream>>>(x, xb, (int)(XN / 4));
  cast_f32_bf16<<<(int)(WN / 4 / 256), 256, 0, stream>>>(Wq, Wqb, (int)(WN / 4));
  cast_f32_bf16<<<(int)(WN / 4 / 256), 256, 0, stream>>>(Wk, Wkb, (int)(WN / 4));
  cast_f32_bf16<<<(int)(WN / 4 / 256), 256, 0, stream>>>(Wv, Wvb, (int)(WN / 4));
  cast_f32_bf16<<<(int)(WN / 4 / 256), 256, 0, stream>>>(Wo, Wob, (int)(WN / 4));

  dim3 gg(D_ / 128, M_ / 128);  // (8, 64)
  gemm_bt<0><<<gg, 256, 0, stream>>>(xb, Wqb, Qb, M_, D_, D_);
  gemm_bt<0><<<gg, 256, 0, stream>>>(xb, Wkb, Kb, M_, D_, D_);
  gemm_bt<1><<<gg, 256, 0, stream>>>(xb, Wvb, Vtb, M_, D_, D_);

  flash_attn<<<dim3(16, B_ * H_), 256, 0, stream>>>(Qb, Kb, Vtb, Ob);

  gemm_bt<2><<<gg, 256, 0, stream>>>(Ob, Wob, d_out, M_, D_, D_);
}

// Round 5
// 346.905 us; speedup vs baseline: 1.9660x; 1.4481x over previous
//
#include <hip/hip_runtime.h>
#include <stdint.h>

#define B_  4
#define S_  2048
#define D_  1024
#define H_  16
#define DK_ 64
#define M_  (B_ * S_)   // 8192

typedef __attribute__((ext_vector_type(4))) float  f32x4;
typedef __attribute__((ext_vector_type(8))) __bf16 bf16x8;
typedef __attribute__((ext_vector_type(4))) unsigned short us4;

__device__ __forceinline__ unsigned short cvt_bf16(float f) {
  unsigned u = __float_as_uint(f);
  return (unsigned short)((u + 0x7fffu + ((u >> 16) & 1u)) >> 16);
}

__device__ __forceinline__ f32x4 mfma16(bf16x8 a, bf16x8 b, f32x4 c) {
  return __builtin_amdgcn_mfma_f32_16x16x32_bf16(a, b, c, 0, 0, 0);
}

__device__ __forceinline__ void async16(const void* g, void* l) {
  __builtin_amdgcn_global_load_lds(
      (const __attribute__((address_space(1))) void*)g,
      (__attribute__((address_space(3))) void*)l, 16, 0, 0);
}

// ---------------------------------------------------------------- cast kernel
__global__ void cast_f32_bf16(const float* __restrict__ in,
                              unsigned short* __restrict__ out, int n4) {
  int i = blockIdx.x * blockDim.x + threadIdx.x;
  if (i >= n4) return;
  f32x4 v = ((const f32x4*)in)[i];
  us4 o;
  o[0] = cvt_bf16(v[0]); o[1] = cvt_bf16(v[1]);
  o[2] = cvt_bf16(v[2]); o[3] = cvt_bf16(v[3]);
  ((us4*)out)[i] = o;
}

// ---------------------------------------------------------------- GEMM C = A @ W^T
// A: [M,K] bf16 row-major.  Bm (=W): [N,K] bf16 row-major.
// OUTMODE 0: bf16 [M,N].  1: bf16 transposed V layout [(m>>11)*1024+n][m&2047].
// OUTMODE 2: f32 [M,N].
template <int OUTMODE>
__global__ __launch_bounds__(256) void gemm_bt(
    const unsigned short* __restrict__ A,
    const unsigned short* __restrict__ Bm,
    void* __restrict__ Cp, int Mdim, int Ndim, int Kdim) {
  constexpr int BM = 128, BN = 128, BK = 32;
  __shared__ __align__(16) unsigned short As[BM * BK];
  __shared__ __align__(16) unsigned short Bs[BN * BK];

  const int tid = threadIdx.x;
  const int w = tid >> 6, l = tid & 63;
  const int l16 = l & 15, lg = l >> 4;
  const int wr = w >> 1, wc = w & 1;
  const int rowA0 = blockIdx.y * BM;
  const int rowB0 = blockIdx.x * BN;
  const int l4 = l >> 2;          // row within a 16-row chunk
  const int lk = (l & 3) * 8;     // k-element offset

  f32x4 acc[4][4] = {};

  for (int kt = 0; kt < Kdim; kt += BK) {
#pragma unroll
    for (int j = 0; j < 2; ++j) {
      const int chunk = j * 4 + w;        // 0..7, wave-uniform
      const int r = chunk * 16 + l4;
      async16(A  + (size_t)(rowA0 + r) * Kdim + kt + lk, &As[chunk * 512]);
      async16(Bm + (size_t)(rowB0 + r) * Kdim + kt + lk, &Bs[chunk * 512]);
    }
    __syncthreads();
    bf16x8 af[4], bfr[4];
#pragma unroll
    for (int m = 0; m < 4; ++m)
      af[m] = *(const bf16x8*)&As[(wr * 64 + m * 16 + l16) * BK + lg * 8];
#pragma unroll
    for (int n = 0; n < 4; ++n)
      bfr[n] = *(const bf16x8*)&Bs[(wc * 64 + n * 16 + l16) * BK + lg * 8];
#pragma unroll
    for (int m = 0; m < 4; ++m)
#pragma unroll
      for (int n = 0; n < 4; ++n)
        acc[m][n] = mfma16(af[m], bfr[n], acc[m][n]);
    __syncthreads();
  }

  const int rb = rowA0 + wr * 64;
  const int cb = rowB0 + wc * 64;
  if constexpr (OUTMODE == 2) {
    float* C = (float*)Cp;
#pragma unroll
    for (int m = 0; m < 4; ++m)
#pragma unroll
      for (int n = 0; n < 4; ++n) {
        const int r0 = rb + m * 16 + lg * 4;
        const int c0 = cb + n * 16 + l16;
#pragma unroll
        for (int j = 0; j < 4; ++j)
          C[(size_t)(r0 + j) * Ndim + c0] = acc[m][n][j];
      }
  } else if constexpr (OUTMODE == 0) {
    unsigned short* C = (unsigned short*)Cp;
#pragma unroll
    for (int m = 0; m < 4; ++m)
#pragma unroll
      for (int n = 0; n < 4; ++n) {
        const int r0 = rb + m * 16 + lg * 4;
        const int c0 = cb + n * 16 + l16;
#pragma unroll
        for (int j = 0; j < 4; ++j)
          C[(size_t)(r0 + j) * Ndim + c0] = cvt_bf16(acc[m][n][j]);
      }
  } else {  // V transposed: Vt[(b*1024 + n)][s], s = m & 2047, b = m >> 11
    unsigned short* C = (unsigned short*)Cp;
#pragma unroll
    for (int m = 0; m < 4; ++m)
#pragma unroll
      for (int n = 0; n < 4; ++n) {
        const int r0 = rb + m * 16 + lg * 4;   // multiple of 4
        const int c0 = cb + n * 16 + l16;
        us4 v;
#pragma unroll
        for (int j = 0; j < 4; ++j) v[j] = cvt_bf16(acc[m][n][j]);
        *(us4*)&C[((size_t)(r0 >> 11) * 1024 + c0) * 2048 + (r0 & 2047)] = v;
      }
  }
}

// ---------------------------------------------------------------- flash attention
// One block = one (b,h) x paired q-tiles {x, 31-x}. 4 waves x (16 rows A + 16
// rows B), processed SEQUENTIALLY per KV tile (caps live registers ~105 so
// __launch_bounds__(256,4) fits 128 VGPRs with NO scratch spill — round-4's
// 468 MB of phantom WRITE_SIZE was spill traffic at VGPR_Count=64).
// Softmax is macro-inlined (no lambda -> no outlining/array-to-scratch risk).
// XCD swizzle: all 16 pair-blocks of one bh land on the same XCD so K/V is
// fetched from HBM once per bh (32 MB total), not once per XCD-replica.

#define SMX(sc, mr, sr, oa, P, diag, rb, kv0)                                \
  do {                                                                       \
    _Pragma("unroll") for (int nc_ = 0; nc_ < 4; ++nc_)                      \
        _Pragma("unroll") for (int j_ = 0; j_ < 4; ++j_)                     \
            sc[nc_][j_] *= 0.125f;                                           \
    if (diag) {                                                              \
      _Pragma("unroll") for (int nc_ = 0; nc_ < 4; ++nc_) {                  \
        const int col_ = (kv0) + nc_ * 16 + l16;                             \
        _Pragma("unroll") for (int j_ = 0; j_ < 4; ++j_)                     \
            if (col_ > (rb) + j_) sc[nc_][j_] = -INFINITY;                   \
      }                                                                      \
    }                                                                        \
    _Pragma("unroll") for (int j_ = 0; j_ < 4; ++j_) {                       \
      float t_ = fmaxf(fmaxf(sc[0][j_], sc[1][j_]),                          \
                       fmaxf(sc[2][j_], sc[3][j_]));                         \
      t_ = fmaxf(t_, __shfl_xor(t_, 1));                                     \
      t_ = fmaxf(t_, __shfl_xor(t_, 2));                                     \
      t_ = fmaxf(t_, __shfl_xor(t_, 4));                                     \
      t_ = fmaxf(t_, __shfl_xor(t_, 8));                                     \
      const float mnew_ = fmaxf(mr[j_], t_);                                 \
      float rs_ = 0.f;                                                       \
      _Pragma("unroll") for (int nc_ = 0; nc_ < 4; ++nc_) {                  \
        const float p_ = __expf(sc[nc_][j_] - mnew_);                        \
        rs_ += p_;                                                           \
        P[lg * 4 + j_][nc_ * 16 + l16] = cvt_bf16(p_);                       \
      }                                                                      \
      rs_ += __shfl_xor(rs_, 1);                                             \
      rs_ += __shfl_xor(rs_, 2);                                             \
      rs_ += __shfl_xor(rs_, 4);                                             \
      rs_ += __shfl_xor(rs_, 8);                                             \
      const float al_ = __expf(mr[j_] - mnew_);                              \
      sr[j_] = sr[j_] * al_ + rs_;                                           \
      mr[j_] = mnew_;                                                        \
      _Pragma("unroll") for (int d_ = 0; d_ < 4; ++d_) oa[d_][j_] *= al_;    \
    }                                                                        \
  } while (0)

__global__ __launch_bounds__(256, 4) void flash_attn(
    const unsigned short* __restrict__ Q,
    const unsigned short* __restrict__ K,
    const unsigned short* __restrict__ Vt,
    unsigned short* __restrict__ O) {
  const int bid  = blockIdx.x;                    // 0..1023
  const int virt = (bid & 7) * 128 + (bid >> 3);  // XCD-grouped remap
  const int bh   = virt >> 4;                     // 0..63 (8 bh per XCD)
  const int x    = virt & 15;                     // 0..15 pair index
  const int b = bh >> 4, h = bh & 15;
  const int tid = threadIdx.x;
  const int w = tid >> 6, l = tid & 63;
  const int l16 = l & 15, lg = l >> 4;

  __shared__ __align__(16) unsigned short Ks[64 * 64];  // [s][dk] swizzled
  __shared__ __align__(16) unsigned short Vs[64 * 64];  // [dk][s] swizzled
  __shared__ __align__(16) unsigned short PA[4][16][72];
  __shared__ __align__(16) unsigned short PB[4][16][72];

  const int tA = x, tB = 31 - x;  // tA < tB always

  const size_t qkbase = (size_t)(b * S_) * D_ + h * DK_;
  const size_t vbase  = ((size_t)(b * D_) + h * DK_) * S_;

  const int rA = tA * 64 + w * 16 + l16;
  const int rB = tB * 64 + w * 16 + l16;
  bf16x8 qfA[2], qfB[2];
  qfA[0] = *(const bf16x8*)&Q[qkbase + (size_t)rA * D_ + lg * 8];
  qfA[1] = *(const bf16x8*)&Q[qkbase + (size_t)rA * D_ + 32 + lg * 8];
  qfB[0] = *(const bf16x8*)&Q[qkbase + (size_t)rB * D_ + lg * 8];
  qfB[1] = *(const bf16x8*)&Q[qkbase + (size_t)rB * D_ + 32 + lg * 8];

  float mA[4], sA[4], mB[4], sB[4];
  f32x4 oA[4] = {}, oB[4] = {};
#pragma unroll
  for (int j = 0; j < 4; ++j) {
    mA[j] = mB[j] = -INFINITY;
    sA[j] = sB[j] = 0.f;
  }

  const int rbA = tA * 64 + w * 16 + lg * 4;  // +j = global q row (set A)
  const int rbB = tB * 64 + w * 16 + lg * 4;

  for (int kv = 0; kv <= tB; ++kv) {
    const int kv0 = kv * 64;
    if (kv) __syncthreads();  // previous tile fully consumed before overwrite
    // stage K tile [64 s][64 dk] and V tile [64 dk][64 s], 16B chunks,
    // inverse-swizzled source so swizzled reads see logical data (rule #21)
#pragma unroll
    for (int c = 0; c < 2; ++c) {
      const int ci = c * 256 + w * 64;  // wave-uniform chunk base
      const int i  = ci + l;            // per-lane chunk 0..511
      const int r  = i >> 3;            // tile row
      const int cc = (i & 7) ^ (r & 7); // swizzled 16B column
      async16(K  + qkbase + (size_t)(kv0 + r) * D_ + cc * 8, &Ks[ci * 8]);
      async16(Vt + vbase  + (size_t)r * S_ + kv0 + cc * 8,   &Vs[ci * 8]);
    }
    __syncthreads();  // compiler drains vmcnt before barrier -> staging done

    // ---- A pass (wave-uniform predicate) ----
    if (kv <= tA) {
      f32x4 sc[4] = {};
#pragma unroll
      for (int nc = 0; nc < 4; ++nc) {
        const int r = nc * 16 + l16;
#pragma unroll
        for (int ks = 0; ks < 2; ++ks) {
          const int byte = (r * 128 + ks * 64 + lg * 16) ^ ((r & 7) << 4);
          bf16x8 kf = *(const bf16x8*)((const char*)Ks + byte);
          sc[nc] = mfma16(qfA[ks], kf, sc[nc]);
        }
      }
      SMX(sc, mA, sA, oA, PA[w], kv == tA, rbA, kv0);
      __asm__ volatile("s_waitcnt lgkmcnt(0)" ::: "memory");
      bf16x8 pa0 = *(const bf16x8*)&PA[w][l16][lg * 8];
      bf16x8 pa1 = *(const bf16x8*)&PA[w][l16][32 + lg * 8];
#pragma unroll
      for (int d = 0; d < 4; ++d) {
        const int r = d * 16 + l16;
#pragma unroll
        for (int ks = 0; ks < 2; ++ks) {
          const int byte = (r * 128 + ks * 64 + lg * 16) ^ ((r & 7) << 4);
          bf16x8 vf = *(const bf16x8*)((const char*)Vs + byte);
          oA[d] = mfma16(ks ? pa1 : pa0, vf, oA[d]);
        }
      }
    }

    // ---- B pass (always active) ----
    {
      f32x4 sc[4] = {};
#pragma unroll
      for (int nc = 0; nc < 4; ++nc) {
        const int r = nc * 16 + l16;
#pragma unroll
        for (int ks = 0; ks < 2; ++ks) {
          const int byte = (r * 128 + ks * 64 + lg * 16) ^ ((r & 7) << 4);
          bf16x8 kf = *(const bf16x8*)((const char*)Ks + byte);
          sc[nc] = mfma16(qfB[ks], kf, sc[nc]);
        }
      }
      SMX(sc, mB, sB, oB, PB[w], kv == tB, rbB, kv0);
      __asm__ volatile("s_waitcnt lgkmcnt(0)" ::: "memory");
      bf16x8 pb0 = *(const bf16x8*)&PB[w][l16][lg * 8];
      bf16x8 pb1 = *(const bf16x8*)&PB[w][l16][32 + lg * 8];
#pragma unroll
      for (int d = 0; d < 4; ++d) {
        const int r = d * 16 + l16;
#pragma unroll
        for (int ks = 0; ks < 2; ++ks) {
          const int byte = (r * 128 + ks * 64 + lg * 16) ^ ((r & 7) << 4);
          bf16x8 vf = *(const bf16x8*)((const char*)Vs + byte);
          oB[d] = mfma16(ks ? pb1 : pb0, vf, oB[d]);
        }
      }
    }
  }

#pragma unroll
  for (int d = 0; d < 4; ++d)
#pragma unroll
    for (int j = 0; j < 4; ++j) {
      O[((size_t)(b * S_) + rbA + j) * D_ + h * DK_ + d * 16 + l16] =
          cvt_bf16(oA[d][j] / sA[j]);
      O[((size_t)(b * S_) + rbB + j) * D_ + h * DK_ + d * 16 + l16] =
          cvt_bf16(oB[d][j] / sB[j]);
    }
}

// ---------------------------------------------------------------- launch
extern "C" void kernel_launch(void* const* d_in, const int* in_sizes, int n_in,
                              void* d_out, int out_size, void* d_ws,
                              size_t ws_size, hipStream_t stream) {
  const float* x  = (const float*)d_in[0];
  const float* Wq = (const float*)d_in[1];
  const float* Wk = (const float*)d_in[2];
  const float* Wv = (const float*)d_in[3];
  const float* Wo = (const float*)d_in[4];

  const size_t XN = (size_t)M_ * D_;   // 8388608
  const size_t WN = (size_t)D_ * D_;   // 1048576
  unsigned short* xb  = (unsigned short*)d_ws;
  unsigned short* Wqb = xb + XN;
  unsigned short* Wkb = Wqb + WN;
  unsigned short* Wvb = Wkb + WN;
  unsigned short* Wob = Wvb + WN;
  unsigned short* Qb  = Wob + WN;
  unsigned short* Kb  = Qb + XN;
  unsigned short* Vtb = Kb + XN;
  unsigned short* Ob  = Vtb + XN;

  cast_f32_bf16<<<(int)(XN / 4 / 256), 256, 0, stream>>>(x, xb, (int)(XN / 4));
  cast_f32_bf16<<<(int)(WN / 4 / 256), 256, 0, stream>>>(Wq, Wqb, (int)(WN / 4));
  cast_f32_bf16<<<(int)(WN / 4 / 256), 256, 0, stream>>>(Wk, Wkb, (int)(WN / 4));
  cast_f32_bf16<<<(int)(WN / 4 / 256), 256, 0, stream>>>(Wv, Wvb, (int)(WN / 4));
  cast_f32_bf16<<<(int)(WN / 4 / 256), 256, 0, stream>>>(Wo, Wob, (int)(WN / 4));

  dim3 gg(D_ / 128, M_ / 128);  // (8, 64)
  gemm_bt<0><<<gg, 256, 0, stream>>>(xb, Wqb, Qb, M_, D_, D_);
  gemm_bt<0><<<gg, 256, 0, stream>>>(xb, Wkb, Kb, M_, D_, D_);
  gemm_bt<1><<<gg, 256, 0, stream>>>(xb, Wvb, Vtb, M_, D_, D_);

  flash_attn<<<dim3(1024), 256, 0, stream>>>(Qb, Kb, Vtb, Ob);

  gemm_bt<2><<<gg, 256, 0, stream>>>(Ob, Wob, d_out, M_, D_, D_);
}

// Round 6
// 318.165 us; speedup vs baseline: 2.1436x; 1.0903x over previous
//
#include <hip/hip_runtime.h>
#include <stdint.h>

#define B_  4
#define S_  2048
#define D_  1024
#define H_  16
#define DK_ 64
#define M_  (B_ * S_)   // 8192

typedef __attribute__((ext_vector_type(4))) float  f32x4;
typedef __attribute__((ext_vector_type(8))) __bf16 bf16x8;
typedef __attribute__((ext_vector_type(4))) unsigned short us4;

__device__ __forceinline__ unsigned short cvt_bf16(float f) {
  unsigned u = __float_as_uint(f);
  return (unsigned short)((u + 0x7fffu + ((u >> 16) & 1u)) >> 16);
}

__device__ __forceinline__ f32x4 mfma16(bf16x8 a, bf16x8 b, f32x4 c) {
  return __builtin_amdgcn_mfma_f32_16x16x32_bf16(a, b, c, 0, 0, 0);
}

__device__ __forceinline__ void async16(const void* g, void* l) {
  __builtin_amdgcn_global_load_lds(
      (const __attribute__((address_space(1))) void*)g,
      (__attribute__((address_space(3))) void*)l, 16, 0, 0);
}

// ------------------------------------------------- fused cast (5 tensors -> 1 launch)
// dst is the contiguous ws region [xb | Wqb | Wkb | Wvb | Wob].
#define XN4_ 2097152  // (M_*D_)/4
#define WN4_ 262144   // (D_*D_)/4
__global__ void cast_all(const float* __restrict__ x,
                         const float* __restrict__ wq,
                         const float* __restrict__ wk,
                         const float* __restrict__ wv,
                         const float* __restrict__ wo,
                         unsigned short* __restrict__ dst) {
  const int i = blockIdx.x * blockDim.x + threadIdx.x;
  const float* src;
  int k;
  if (i < XN4_) {
    src = x; k = i;
  } else {
    const int j = i - XN4_;
    const int wsel = j >> 18;          // WN4_ = 2^18
    k = j & (WN4_ - 1);
    src = (wsel == 0) ? wq : (wsel == 1) ? wk : (wsel == 2) ? wv : wo;
  }
  f32x4 v = ((const f32x4*)src)[k];
  us4 o;
  o[0] = cvt_bf16(v[0]); o[1] = cvt_bf16(v[1]);
  o[2] = cvt_bf16(v[2]); o[3] = cvt_bf16(v[3]);
  ((us4*)dst)[i] = o;
}

// ---------------------------------------------------------------- GEMM C = A @ W^T
// A: [M,K] bf16 row-major.  Bm: [N,K] bf16 row-major.
// OUTMODE 2: f32 [M,N] to Cp.
// OUTMODE 3: fused-QKV routing — Bm is [3072,1024] (Wq|Wk|Wv rows); cols
//   0-1023 -> Qo bf16 [M,1024]; 1024-2047 -> Ko; 2048-3071 -> Vto transposed
//   layout [(m>>11)*1024 + n][m&2047].
template <int OUTMODE>
__global__ __launch_bounds__(256) void gemm_bt(
    const unsigned short* __restrict__ A,
    const unsigned short* __restrict__ Bm,
    void* __restrict__ Cp,
    unsigned short* __restrict__ Qo, unsigned short* __restrict__ Ko,
    unsigned short* __restrict__ Vto,
    int Ndim, int Kdim) {
  constexpr int BM = 128, BN = 128, BK = 32;
  __shared__ __align__(16) unsigned short As[BM * BK];
  __shared__ __align__(16) unsigned short Bs[BN * BK];

  const int tid = threadIdx.x;
  const int w = tid >> 6, l = tid & 63;
  const int l16 = l & 15, lg = l >> 4;
  const int wr = w >> 1, wc = w & 1;
  const int rowA0 = blockIdx.y * BM;
  const int rowB0 = blockIdx.x * BN;
  const int l4 = l >> 2;          // row within a 16-row chunk
  const int lk = (l & 3) * 8;     // k-element offset

  f32x4 acc[4][4] = {};

  for (int kt = 0; kt < Kdim; kt += BK) {
#pragma unroll
    for (int j = 0; j < 2; ++j) {
      const int chunk = j * 4 + w;        // 0..7, wave-uniform
      const int r = chunk * 16 + l4;
      async16(A  + (size_t)(rowA0 + r) * Kdim + kt + lk, &As[chunk * 512]);
      async16(Bm + (size_t)(rowB0 + r) * Kdim + kt + lk, &Bs[chunk * 512]);
    }
    __syncthreads();
    bf16x8 af[4], bfr[4];
#pragma unroll
    for (int m = 0; m < 4; ++m)
      af[m] = *(const bf16x8*)&As[(wr * 64 + m * 16 + l16) * BK + lg * 8];
#pragma unroll
    for (int n = 0; n < 4; ++n)
      bfr[n] = *(const bf16x8*)&Bs[(wc * 64 + n * 16 + l16) * BK + lg * 8];
#pragma unroll
    for (int m = 0; m < 4; ++m)
#pragma unroll
      for (int n = 0; n < 4; ++n)
        acc[m][n] = mfma16(af[m], bfr[n], acc[m][n]);
    __syncthreads();
  }

  const int rb = rowA0 + wr * 64;
  const int cb = rowB0 + wc * 64;
  if constexpr (OUTMODE == 2) {
    float* C = (float*)Cp;
#pragma unroll
    for (int m = 0; m < 4; ++m)
#pragma unroll
      for (int n = 0; n < 4; ++n) {
        const int r0 = rb + m * 16 + lg * 4;
        const int c0 = cb + n * 16 + l16;
#pragma unroll
        for (int j = 0; j < 4; ++j)
          C[(size_t)(r0 + j) * Ndim + c0] = acc[m][n][j];
      }
  } else {  // OUTMODE 3: fused QKV routing (region is block-uniform)
    const int region = cb >> 10;
    const int cbl = cb & 1023;
    if (region < 2) {
      unsigned short* C = region ? Ko : Qo;
#pragma unroll
      for (int m = 0; m < 4; ++m)
#pragma unroll
        for (int n = 0; n < 4; ++n) {
          const int r0 = rb + m * 16 + lg * 4;
          const int c0 = cbl + n * 16 + l16;
#pragma unroll
          for (int j = 0; j < 4; ++j)
            C[(size_t)(r0 + j) * 1024 + c0] = cvt_bf16(acc[m][n][j]);
        }
    } else {  // V transposed
#pragma unroll
      for (int m = 0; m < 4; ++m)
#pragma unroll
        for (int n = 0; n < 4; ++n) {
          const int r0 = rb + m * 16 + lg * 4;   // multiple of 4
          const int c0 = cbl + n * 16 + l16;
          us4 v;
#pragma unroll
          for (int j = 0; j < 4; ++j) v[j] = cvt_bf16(acc[m][n][j]);
          *(us4*)&Vto[((size_t)(r0 >> 11) * 1024 + c0) * 2048 + (r0 & 2047)] = v;
        }
    }
  }
}

// ---------------------------------------------------------------- flash attention
// Paired q-tiles {x, 31-x} per (b,h); A/B passes serialized (no spills at
// (256,4)); K/V staged once per tile in XOR-swizzled LDS; XCD-grouped blocks.
// Softmax: raw-score max tracking, scale folded into exp2 argument
// (exact: 0.125*log2e applied in f32); defer-max vote skips rescale when the
// running max didn't grow; s_setprio(1) around MFMA clusters (T5).

#define KS_ 0.1803368801f  // 0.125 * log2(e)

#define SMX(sc, mr, sr, oa, P, diag, rb, kv0)                                \
  do {                                                                       \
    if (diag) {                                                              \
      _Pragma("unroll") for (int nc_ = 0; nc_ < 4; ++nc_) {                  \
        const int col_ = (kv0) + nc_ * 16 + l16;                             \
        _Pragma("unroll") for (int j_ = 0; j_ < 4; ++j_)                     \
            if (col_ > (rb) + j_) sc[nc_][j_] = -INFINITY;                   \
      }                                                                      \
    }                                                                        \
    _Pragma("unroll") for (int j_ = 0; j_ < 4; ++j_) {                       \
      float t_ = fmaxf(fmaxf(sc[0][j_], sc[1][j_]),                          \
                       fmaxf(sc[2][j_], sc[3][j_]));                         \
      t_ = fmaxf(t_, __shfl_xor(t_, 1));                                     \
      t_ = fmaxf(t_, __shfl_xor(t_, 2));                                     \
      t_ = fmaxf(t_, __shfl_xor(t_, 4));                                     \
      t_ = fmaxf(t_, __shfl_xor(t_, 8));                                     \
      const bool st_ = __all(t_ <= mr[j_]);   /* wave-uniform: no growth */  \
      const float mnew_ = st_ ? mr[j_] : fmaxf(mr[j_], t_);                  \
      float rs_ = 0.f;                                                       \
      _Pragma("unroll") for (int nc_ = 0; nc_ < 4; ++nc_) {                  \
        const float p_ = exp2f((sc[nc_][j_] - mnew_) * KS_);                 \
        rs_ += p_;                                                           \
        P[lg * 4 + j_][nc_ * 16 + l16] = cvt_bf16(p_);                       \
      }                                                                      \
      rs_ += __shfl_xor(rs_, 1);                                             \
      rs_ += __shfl_xor(rs_, 2);                                             \
      rs_ += __shfl_xor(rs_, 4);                                             \
      rs_ += __shfl_xor(rs_, 8);                                             \
      if (st_) {                                                             \
        sr[j_] += rs_;                                                       \
      } else {                                                               \
        const float al_ = exp2f((mr[j_] - mnew_) * KS_);                     \
        sr[j_] = sr[j_] * al_ + rs_;                                         \
        mr[j_] = mnew_;                                                      \
        _Pragma("unroll") for (int d_ = 0; d_ < 4; ++d_) oa[d_][j_] *= al_;  \
      }                                                                      \
    }                                                                        \
  } while (0)

__global__ __launch_bounds__(256, 4) void flash_attn(
    const unsigned short* __restrict__ Q,
    const unsigned short* __restrict__ K,
    const unsigned short* __restrict__ Vt,
    unsigned short* __restrict__ O) {
  const int bid  = blockIdx.x;                    // 0..1023
  const int virt = (bid & 7) * 128 + (bid >> 3);  // XCD-grouped remap
  const int bh   = virt >> 4;                     // 0..63 (8 bh per XCD)
  const int x    = virt & 15;                     // 0..15 pair index
  const int b = bh >> 4, h = bh & 15;
  const int tid = threadIdx.x;
  const int w = tid >> 6, l = tid & 63;
  const int l16 = l & 15, lg = l >> 4;

  __shared__ __align__(16) unsigned short Ks[64 * 64];  // [s][dk] swizzled
  __shared__ __align__(16) unsigned short Vs[64 * 64];  // [dk][s] swizzled
  __shared__ __align__(16) unsigned short PA[4][16][72];
  __shared__ __align__(16) unsigned short PB[4][16][72];

  const int tA = x, tB = 31 - x;  // tA < tB always

  const size_t qkbase = (size_t)(b * S_) * D_ + h * DK_;
  const size_t vbase  = ((size_t)(b * D_) + h * DK_) * S_;

  const int rA = tA * 64 + w * 16 + l16;
  const int rB = tB * 64 + w * 16 + l16;
  bf16x8 qfA[2], qfB[2];
  qfA[0] = *(const bf16x8*)&Q[qkbase + (size_t)rA * D_ + lg * 8];
  qfA[1] = *(const bf16x8*)&Q[qkbase + (size_t)rA * D_ + 32 + lg * 8];
  qfB[0] = *(const bf16x8*)&Q[qkbase + (size_t)rB * D_ + lg * 8];
  qfB[1] = *(const bf16x8*)&Q[qkbase + (size_t)rB * D_ + 32 + lg * 8];

  float mA[4], sA[4], mB[4], sB[4];
  f32x4 oA[4] = {}, oB[4] = {};
#pragma unroll
  for (int j = 0; j < 4; ++j) {
    mA[j] = mB[j] = -INFINITY;
    sA[j] = sB[j] = 0.f;
  }

  const int rbA = tA * 64 + w * 16 + lg * 4;  // +j = global q row (set A)
  const int rbB = tB * 64 + w * 16 + lg * 4;

  for (int kv = 0; kv <= tB; ++kv) {
    const int kv0 = kv * 64;
    if (kv) __syncthreads();  // previous tile fully consumed before overwrite
#pragma unroll
    for (int c = 0; c < 2; ++c) {
      const int ci = c * 256 + w * 64;  // wave-uniform chunk base
      const int i  = ci + l;            // per-lane chunk 0..511
      const int r  = i >> 3;            // tile row
      const int cc = (i & 7) ^ (r & 7); // swizzled 16B column
      async16(K  + qkbase + (size_t)(kv0 + r) * D_ + cc * 8, &Ks[ci * 8]);
      async16(Vt + vbase  + (size_t)r * S_ + kv0 + cc * 8,   &Vs[ci * 8]);
    }
    __syncthreads();  // staging complete

    // ---- A pass (wave-uniform predicate) ----
    if (kv <= tA) {
      f32x4 sc[4] = {};
      __builtin_amdgcn_s_setprio(1);
#pragma unroll
      for (int nc = 0; nc < 4; ++nc) {
        const int r = nc * 16 + l16;
#pragma unroll
        for (int ks = 0; ks < 2; ++ks) {
          const int byte = (r * 128 + ks * 64 + lg * 16) ^ ((r & 7) << 4);
          bf16x8 kf = *(const bf16x8*)((const char*)Ks + byte);
          sc[nc] = mfma16(qfA[ks], kf, sc[nc]);
        }
      }
      __builtin_amdgcn_s_setprio(0);
      SMX(sc, mA, sA, oA, PA[w], kv == tA, rbA, kv0);
      __asm__ volatile("s_waitcnt lgkmcnt(0)" ::: "memory");
      bf16x8 pa0 = *(const bf16x8*)&PA[w][l16][lg * 8];
      bf16x8 pa1 = *(const bf16x8*)&PA[w][l16][32 + lg * 8];
      __builtin_amdgcn_s_setprio(1);
#pragma unroll
      for (int d = 0; d < 4; ++d) {
        const int r = d * 16 + l16;
#pragma unroll
        for (int ks = 0; ks < 2; ++ks) {
          const int byte = (r * 128 + ks * 64 + lg * 16) ^ ((r & 7) << 4);
          bf16x8 vf = *(const bf16x8*)((const char*)Vs + byte);
          oA[d] = mfma16(ks ? pa1 : pa0, vf, oA[d]);
        }
      }
      __builtin_amdgcn_s_setprio(0);
    }

    // ---- B pass (always active) ----
    {
      f32x4 sc[4] = {};
      __builtin_amdgcn_s_setprio(1);
#pragma unroll
      for (int nc = 0; nc < 4; ++nc) {
        const int r = nc * 16 + l16;
#pragma unroll
        for (int ks = 0; ks < 2; ++ks) {
          const int byte = (r * 128 + ks * 64 + lg * 16) ^ ((r & 7) << 4);
          bf16x8 kf = *(const bf16x8*)((const char*)Ks + byte);
          sc[nc] = mfma16(qfB[ks], kf, sc[nc]);
        }
      }
      __builtin_amdgcn_s_setprio(0);
      SMX(sc, mB, sB, oB, PB[w], kv == tB, rbB, kv0);
      __asm__ volatile("s_waitcnt lgkmcnt(0)" ::: "memory");
      bf16x8 pb0 = *(const bf16x8*)&PB[w][l16][lg * 8];
      bf16x8 pb1 = *(const bf16x8*)&PB[w][l16][32 + lg * 8];
      __builtin_amdgcn_s_setprio(1);
#pragma unroll
      for (int d = 0; d < 4; ++d) {
        const int r = d * 16 + l16;
#pragma unroll
        for (int ks = 0; ks < 2; ++ks) {
          const int byte = (r * 128 + ks * 64 + lg * 16) ^ ((r & 7) << 4);
          bf16x8 vf = *(const bf16x8*)((const char*)Vs + byte);
          oB[d] = mfma16(ks ? pb1 : pb0, vf, oB[d]);
        }
      }
      __builtin_amdgcn_s_setprio(0);
    }
  }

#pragma unroll
  for (int j = 0; j < 4; ++j) {
    const float iA = __builtin_amdgcn_rcpf(sA[j]);
    const float iB = __builtin_amdgcn_rcpf(sB[j]);
#pragma unroll
    for (int d = 0; d < 4; ++d) {
      O[((size_t)(b * S_) + rbA + j) * D_ + h * DK_ + d * 16 + l16] =
          cvt_bf16(oA[d][j] * iA);
      O[((size_t)(b * S_) + rbB + j) * D_ + h * DK_ + d * 16 + l16] =
          cvt_bf16(oB[d][j] * iB);
    }
  }
}

// ---------------------------------------------------------------- launch
extern "C" void kernel_launch(void* const* d_in, const int* in_sizes, int n_in,
                              void* d_out, int out_size, void* d_ws,
                              size_t ws_size, hipStream_t stream) {
  const float* x  = (const float*)d_in[0];
  const float* Wq = (const float*)d_in[1];
  const float* Wk = (const float*)d_in[2];
  const float* Wv = (const float*)d_in[3];
  const float* Wo = (const float*)d_in[4];

  const size_t XN = (size_t)M_ * D_;   // 8388608
  const size_t WN = (size_t)D_ * D_;   // 1048576
  unsigned short* xb  = (unsigned short*)d_ws;
  unsigned short* Wqb = xb + XN;       // Wq|Wk|Wv contiguous = fused [3072,1024]
  unsigned short* Wob = Wqb + 3 * WN;
  unsigned short* Qb  = Wob + WN;
  unsigned short* Kb  = Qb + XN;
  unsigned short* Vtb = Kb + XN;
  unsigned short* Ob  = Vtb + XN;

  // one fused cast: [x | Wq | Wk | Wv | Wo] -> bf16 ws region
  cast_all<<<(XN4_ + 4 * WN4_) / 256, 256, 0, stream>>>(x, Wq, Wk, Wv, Wo, xb);

  // fused QKV projection: N = 3072, routed epilogue
  gemm_bt<3><<<dim3(24, 64), 256, 0, stream>>>(xb, Wqb, nullptr, Qb, Kb, Vtb,
                                               3072, D_);

  flash_attn<<<dim3(1024), 256, 0, stream>>>(Qb, Kb, Vtb, Ob);

  // output projection: f32 out
  gemm_bt<2><<<dim3(8, 64), 256, 0, stream>>>(Ob, Wob, d_out, nullptr, nullptr,
                                              nullptr, D_, D_);
}